// Round 2
// baseline (350.042 us; speedup 1.0000x reference)
//
#include <hip/hip_runtime.h>
#include <hip/hip_bf16.h>
#include <stdint.h>

#define NN 4096
#define NF 128
#define NSPLIT 16

using f32x4  = __attribute__((ext_vector_type(4))) float;
using bf16x8 = __attribute__((ext_vector_type(8))) __bf16;
using u16x8  = __attribute__((ext_vector_type(8))) uint16_t;

__device__ __forceinline__ uint16_t f2b(float f) {
    union { float f; uint32_t u; } v; v.f = f;
    uint32_t r = v.u + 0x7FFFu + ((v.u >> 16) & 1u);
    return (uint16_t)(r >> 16);
}

__device__ __forceinline__ void gld_lds16(const void* g, void* l) {
    __builtin_amdgcn_global_load_lds(
        (const __attribute__((address_space(1))) uint32_t*)g,
        (__attribute__((address_space(3))) uint32_t*)l,
        16, 0, 0);
}

// ---------------------------------------------------------------------------
// Kernel 1: XW = X@W (one row per block), s_col = XW@a[:128], s_row = XW@a[128:]
// writes XWT (bf16, [128][4096]) for later use as a B^T GEMM operand.
// ---------------------------------------------------------------------------
__global__ void xw_kernel(const float* __restrict__ X, const float* __restrict__ W,
                          const float* __restrict__ a,
                          uint16_t* __restrict__ XWT,
                          float* __restrict__ s_col, float* __restrict__ s_row) {
    __shared__ float xs[NF];
    __shared__ float red[4];
    const int i = blockIdx.x, f = threadIdx.x;
    xs[f] = X[i * NF + f];
    __syncthreads();
    float acc = 0.f;
    #pragma unroll 8
    for (int k = 0; k < NF; ++k) acc += xs[k] * W[k * NF + f];
    XWT[(size_t)f * NN + i] = f2b(acc);
    float sc = acc * a[f];
    float sr = acc * a[NF + f];
    #pragma unroll
    for (int off = 32; off; off >>= 1) {
        sc += __shfl_down(sc, off);
        sr += __shfl_down(sr, off);
    }
    if ((f & 63) == 0) { red[f >> 6] = sc; red[2 + (f >> 6)] = sr; }
    __syncthreads();
    if (f == 0) {
        s_col[i] = red[0] + red[1];
        s_row[i] = red[2] + red[3];
    }
}

// ---------------------------------------------------------------------------
// Kernel 2: fp32 -> bf16 conversion (A matrix), 4 elems/thread
// ---------------------------------------------------------------------------
__global__ void conv_bf16_kernel(const float* __restrict__ in, uint16_t* __restrict__ out) {
    int idx = blockIdx.x * blockDim.x + threadIdx.x;
    float4 v = ((const float4*)in)[idx];
    ushort4 o;
    o.x = f2b(v.x); o.y = f2b(v.y); o.z = f2b(v.z); o.w = f2b(v.w);
    ((ushort4*)out)[idx] = o;
}

// ---------------------------------------------------------------------------
// Kernel 3: denT[j][k] = bf16(exp(leaky_relu(s_row[k] + s_col[j])))
// ---------------------------------------------------------------------------
__global__ void denT_kernel(const float* __restrict__ s_row, const float* __restrict__ s_col,
                            uint16_t* __restrict__ denT) {
    int idx = blockIdx.x * blockDim.x + threadIdx.x;
    int j = idx >> 10;
    int k = (idx & 1023) << 2;
    float sc = s_col[j];
    float4 sr = *(const float4*)(s_row + k);
    float z0 = sc + sr.x; z0 = z0 > 0.f ? z0 : 0.01f * z0;
    float z1 = sc + sr.y; z1 = z1 > 0.f ? z1 : 0.01f * z1;
    float z2 = sc + sr.z; z2 = z2 > 0.f ? z2 : 0.01f * z2;
    float z3 = sc + sr.w; z3 = z3 > 0.f ? z3 : 0.01f * z3;
    ushort4 o;
    o.x = f2b(__expf(z0)); o.y = f2b(__expf(z1));
    o.z = f2b(__expf(z2)); o.w = f2b(__expf(z3));
    *(ushort4*)(denT + (size_t)j * NN + k) = o;
}

// ---------------------------------------------------------------------------
// Shared GEMM core (m97 structure): C[i][j] = sum_k A[i,k] * Bt[j,k]
// 128x128 block tile, BK=32, 4 waves (2x2), 16x16x32 bf16 MFMA, 4x4 frags/wave.
// ---------------------------------------------------------------------------
__device__ __forceinline__ void gemm_core(
    const uint16_t* __restrict__ Ab, const uint16_t* __restrict__ Bt,
    int bm0, int bn0, int kBeg, int kEnd, int K,
    uint16_t* As, uint16_t* Bs, f32x4 acc[4][4]) {
    const int tid  = threadIdx.x;
    const int lane = tid & 63;
    const int wid  = tid >> 6;
    const int wy   = wid >> 1, wx = wid & 1;
    const int quad = lane >> 4, l16 = lane & 15;
    const int byteoff = tid * 16;
    const int srow    = byteoff >> 6;
    const int scol    = (byteoff & 63) >> 1;

    for (int k0 = kBeg; k0 < kEnd; k0 += 32) {
        __syncthreads();
        gld_lds16(Ab + (size_t)(bm0 +      srow) * K + k0 + scol, (char*)As +        byteoff);
        gld_lds16(Ab + (size_t)(bm0 + 64 + srow) * K + k0 + scol, (char*)As + 4096 + byteoff);
        gld_lds16(Bt + (size_t)(bn0 +      srow) * K + k0 + scol, (char*)Bs +        byteoff);
        gld_lds16(Bt + (size_t)(bn0 + 64 + srow) * K + k0 + scol, (char*)Bs + 4096 + byteoff);
        __syncthreads();
        bf16x8 af[4], bf[4];
        #pragma unroll
        for (int mi = 0; mi < 4; ++mi)
            af[mi] = *(const bf16x8*)((const char*)As + ((wy * 64 + mi * 16 + l16) * 64 + quad * 16));
        #pragma unroll
        for (int ni = 0; ni < 4; ++ni)
            bf[ni] = *(const bf16x8*)((const char*)Bs + ((wx * 64 + ni * 16 + l16) * 64 + quad * 16));
        #pragma unroll
        for (int mi = 0; mi < 4; ++mi)
            #pragma unroll
            for (int ni = 0; ni < 4; ++ni)
                acc[mi][ni] = __builtin_amdgcn_mfma_f32_16x16x32_bf16(af[mi], bf[ni], acc[mi][ni], 0, 0, 0);
    }
}

// ---------------------------------------------------------------------------
// Kernel 4: num = A @ den, fused epilogue att = den/num (bf16), stores staged
// through LDS for coalesced dwordx4 writes. LDS epilogue tile stride = 136
// uint16 (272 B: 16B-aligned rows, 272/4 = 68 ≡ 4 mod 32 spreads banks).
// ---------------------------------------------------------------------------
__global__ __launch_bounds__(256) void gemm_att_kernel(
    const uint16_t* __restrict__ Ab, const uint16_t* __restrict__ Bt,
    const float* __restrict__ s_row, const float* __restrict__ s_col,
    uint16_t* __restrict__ att) {
    __shared__ __align__(16) char smem[128 * 272];   // 34816 B; K-loop uses first 16 KB
    uint16_t* As = (uint16_t*)smem;
    uint16_t* Bs = (uint16_t*)(smem + 8192);
    const int bm0 = blockIdx.y * 128, bn0 = blockIdx.x * 128;
    f32x4 acc[4][4];
    #pragma unroll
    for (int mi = 0; mi < 4; ++mi)
        #pragma unroll
        for (int ni = 0; ni < 4; ++ni)
            acc[mi][ni] = (f32x4){0.f, 0.f, 0.f, 0.f};

    gemm_core(Ab, Bt, bm0, bn0, 0, NN, NN, As, Bs, acc);

    const int lane = threadIdx.x & 63, wid = threadIdx.x >> 6;
    const int wy = wid >> 1, wx = wid & 1;
    const int quad = lane >> 4, l16 = lane & 15;

    __syncthreads();   // all waves done reading As/Bs before overwrite
    uint16_t* smem16 = (uint16_t*)smem;

    float srv[4][4];
    #pragma unroll
    for (int mi = 0; mi < 4; ++mi)
        #pragma unroll
        for (int r = 0; r < 4; ++r)
            srv[mi][r] = s_row[bm0 + wy * 64 + mi * 16 + quad * 4 + r];

    #pragma unroll
    for (int ni = 0; ni < 4; ++ni) {
        const int jl = wx * 64 + ni * 16 + l16;
        const float scj = s_col[bn0 + jl];
        #pragma unroll
        for (int mi = 0; mi < 4; ++mi) {
            #pragma unroll
            for (int r = 0; r < 4; ++r) {
                float z = srv[mi][r] + scj;
                z = z > 0.f ? z : 0.01f * z;
                const float den = __expf(z);
                const float num = acc[mi][ni][r];
                float v = den * __builtin_amdgcn_rcpf(num);
                v = (num != 0.f) ? v : 0.f;
                smem16[(wy * 64 + mi * 16 + quad * 4 + r) * 136 + jl] = f2b(v);
            }
        }
    }
    __syncthreads();
    {
        const int t = threadIdx.x;
        const int row = t >> 1, half = t & 1;
        const u16x8* src = (const u16x8*)(smem16 + row * 136 + half * 64);
        u16x8* dst = (u16x8*)(att + (size_t)(bm0 + row) * NN + bn0 + half * 64);
        #pragma unroll
        for (int c = 0; c < 8; ++c) dst[c] = src[c];
    }
}

// ---------------------------------------------------------------------------
// Kernel 5: skinny GEMM split-K: P stored COLUMN-MAJOR per split:
// P[split][j][i] (j = output col 0..127, i = row) -> float4 stores over r.
// ---------------------------------------------------------------------------
__global__ __launch_bounds__(256) void gemm_splitk_kernel(
    const uint16_t* __restrict__ Ab, const uint16_t* __restrict__ Bt,
    float* __restrict__ P) {
    __shared__ __align__(16) uint16_t As[128 * 32];
    __shared__ __align__(16) uint16_t Bs[128 * 32];
    const int bm0 = blockIdx.y * 128;
    const int split = blockIdx.z;
    const int chunk = NN / NSPLIT;
    f32x4 acc[4][4];
    #pragma unroll
    for (int mi = 0; mi < 4; ++mi)
        #pragma unroll
        for (int ni = 0; ni < 4; ++ni)
            acc[mi][ni] = (f32x4){0.f, 0.f, 0.f, 0.f};

    gemm_core(Ab, Bt, bm0, 0, split * chunk, (split + 1) * chunk, NN, As, Bs, acc);

    const int lane = threadIdx.x & 63, wid = threadIdx.x >> 6;
    const int wy = wid >> 1, wx = wid & 1;
    const int quad = lane >> 4, l16 = lane & 15;
    float* Pp = P + (size_t)split * (NN * NF);
    #pragma unroll
    for (int mi = 0; mi < 4; ++mi) {
        const int i0 = bm0 + wy * 64 + mi * 16 + quad * 4;
        #pragma unroll
        for (int ni = 0; ni < 4; ++ni) {
            const int j = wx * 64 + ni * 16 + l16;
            *(f32x4*)(Pp + (size_t)j * NN + i0) = acc[mi][ni];
        }
    }
}

// ---------------------------------------------------------------------------
// Reduce kernels (P is [split][j][i] col-major)
// ---------------------------------------------------------------------------
__global__ void reduce_t_kernel(const float* __restrict__ P, uint16_t* __restrict__ M1T) {
    int idx = blockIdx.x * 256 + threadIdx.x;   // enumerates [f][i] == col-major
    float s = 0.f;
    #pragma unroll
    for (int sp = 0; sp < NSPLIT; ++sp) s += P[(size_t)sp * (NN * NF) + idx];
    M1T[idx] = f2b(s);                           // M1T[f*NN+i] == same layout
}

__global__ void reduce_out_kernel(const float* __restrict__ P, float* __restrict__ out) {
    int idx = blockIdx.x * 256 + threadIdx.x;   // coalesced reads of P
    float s = 0.f;
    #pragma unroll
    for (int sp = 0; sp < NSPLIT; ++sp) s += P[(size_t)sp * (NN * NF) + idx];
    int j = idx >> 12, i = idx & 4095;          // idx = j*4096 + i
    out[(size_t)i * NF + j] = s;                // scattered 4B, absorbed by L2
}

// ---------------------------------------------------------------------------
extern "C" void kernel_launch(void* const* d_in, const int* in_sizes, int n_in,
                              void* d_out, int out_size, void* d_ws, size_t ws_size,
                              hipStream_t stream) {
    (void)in_sizes; (void)n_in; (void)out_size; (void)ws_size;
    const float* X = (const float*)d_in[0];
    const float* A = (const float*)d_in[1];
    const float* W = (const float*)d_in[2];
    const float* a = (const float*)d_in[3];
    float* H = (float*)d_out;

    char* ws = (char*)d_ws;
    uint16_t* Ab   = (uint16_t*)(ws);                          // 32 MB
    uint16_t* denT = (uint16_t*)(ws + ((size_t)32 << 20));     // 32 MB (reused as P)
    float*    P    = (float*)   (ws + ((size_t)32 << 20));     // 32 MB, overlays dead denT
    uint16_t* att  = (uint16_t*)(ws + ((size_t)64 << 20));     // 32 MB
    uint16_t* XWT  = (uint16_t*)(ws + ((size_t)96 << 20));     // 1 MB
    uint16_t* M1T  = (uint16_t*)(ws + ((size_t)97 << 20));     // 1 MB
    float*    s_col= (float*)   (ws + ((size_t)98 << 20));     // 16 KB
    float*    s_row= (float*)   (ws + ((size_t)98 << 20) + 16384);

    // 1. XW + scores (+ XWT bf16)
    xw_kernel<<<NN, NF, 0, stream>>>(X, W, a, XWT, s_col, s_row);
    // 2. A -> bf16
    conv_bf16_kernel<<<(NN * NN / 4) / 256, 256, 0, stream>>>(A, Ab);
    // 3. denT bf16
    denT_kernel<<<(NN * 1024) / 256, 256, 0, stream>>>(s_row, s_col, denT);
    // 4. num = A@den with fused att epilogue
    gemm_att_kernel<<<dim3(32, 32), 256, 0, stream>>>(Ab, denT, s_row, s_col, att);
    // 5. M1 = att @ XW (split-K partials, P overlays denT which is now dead)
    gemm_splitk_kernel<<<dim3(1, 32, NSPLIT), 256, 0, stream>>>(att, XWT, P);
    // 6. reduce -> M1T bf16 (col-major == B^T operand)
    reduce_t_kernel<<<(NN * NF) / 256, 256, 0, stream>>>(P, M1T);
    // 7. H = A @ M1 (split-K partials)
    gemm_splitk_kernel<<<dim3(1, 32, NSPLIT), 256, 0, stream>>>(Ab, M1T, P);
    // 8. reduce -> output
    reduce_out_kernel<<<(NN * NF) / 256, 256, 0, stream>>>(P, H);
}

// Round 3
// 276.343 us; speedup vs baseline: 1.2667x; 1.2667x over previous
//
#include <hip/hip_runtime.h>
#include <hip/hip_bf16.h>
#include <stdint.h>

#define NN 4096
#define NF 128
#define NSPLIT 16

using f32x4  = __attribute__((ext_vector_type(4))) float;
using f32x16 = __attribute__((ext_vector_type(16))) float;
using bf16x8 = __attribute__((ext_vector_type(8))) __bf16;
using u16x8  = __attribute__((ext_vector_type(8))) uint16_t;
using i32x4  = __attribute__((ext_vector_type(4))) int;
using i32x8  = __attribute__((ext_vector_type(8))) int;

__device__ __forceinline__ uint16_t f2b(float f) {
    union { float f; uint32_t u; } v; v.f = f;
    uint32_t r = v.u + 0x7FFFu + ((v.u >> 16) & 1u);
    return (uint16_t)(r >> 16);
}

// pack 4 fp32 -> 4 fp8 e4m3 (OCP) in one dword
__device__ __forceinline__ uint32_t pk_fp8x4(float a, float b, float c, float d) {
    int p = __builtin_amdgcn_cvt_pk_fp8_f32(a, b, 0, false);
    p = __builtin_amdgcn_cvt_pk_fp8_f32(c, d, p, true);
    return (uint32_t)p;
}

__device__ __forceinline__ void gld_lds16(const void* g, void* l) {
    __builtin_amdgcn_global_load_lds(
        (const __attribute__((address_space(1))) uint32_t*)g,
        (__attribute__((address_space(3))) uint32_t*)l,
        16, 0, 0);
}

// ---------------------------------------------------------------------------
// Kernel 1: XW = X@W, s_col = XW@a[:128], s_row = XW@a[128:], XWT bf16
// ---------------------------------------------------------------------------
__global__ void xw_kernel(const float* __restrict__ X, const float* __restrict__ W,
                          const float* __restrict__ a,
                          uint16_t* __restrict__ XWT,
                          float* __restrict__ s_col, float* __restrict__ s_row) {
    __shared__ float xs[NF];
    __shared__ float red[4];
    const int i = blockIdx.x, f = threadIdx.x;
    xs[f] = X[i * NF + f];
    __syncthreads();
    float acc = 0.f;
    #pragma unroll 8
    for (int k = 0; k < NF; ++k) acc += xs[k] * W[k * NF + f];
    XWT[(size_t)f * NN + i] = f2b(acc);
    float sc = acc * a[f];
    float sr = acc * a[NF + f];
    #pragma unroll
    for (int off = 32; off; off >>= 1) {
        sc += __shfl_down(sc, off);
        sr += __shfl_down(sr, off);
    }
    if ((f & 63) == 0) { red[f >> 6] = sc; red[2 + (f >> 6)] = sr; }
    __syncthreads();
    if (f == 0) {
        s_col[i] = red[0] + red[1];
        s_row[i] = red[2] + red[3];
    }
}

// ---------------------------------------------------------------------------
// Kernel 2: A fp32 -> Ab bf16 (for skinny GEMM) AND Ab8 fp8-e4m3 (for big GEMM)
// ---------------------------------------------------------------------------
__global__ void conv_kernel(const float* __restrict__ in,
                            uint16_t* __restrict__ ob16, uint32_t* __restrict__ o8) {
    int idx = blockIdx.x * blockDim.x + threadIdx.x;
    float4 v = ((const float4*)in)[idx];
    ushort4 o;
    o.x = f2b(v.x); o.y = f2b(v.y); o.z = f2b(v.z); o.w = f2b(v.w);
    ((ushort4*)ob16)[idx] = o;
    o8[idx] = pk_fp8x4(v.x, v.y, v.z, v.w);
}

// ---------------------------------------------------------------------------
// Kernel 3: denT8[j][k] = fp8(exp(leaky_relu(s_row[k] + s_col[j])))
// ---------------------------------------------------------------------------
__global__ void denT_kernel(const float* __restrict__ s_row, const float* __restrict__ s_col,
                            uint32_t* __restrict__ denT8) {
    int idx = blockIdx.x * blockDim.x + threadIdx.x;
    int j = idx >> 10;
    int k = (idx & 1023) << 2;
    float sc = s_col[j];
    float4 sr = *(const float4*)(s_row + k);
    float z0 = sc + sr.x; z0 = z0 > 0.f ? z0 : 0.01f * z0;
    float z1 = sc + sr.y; z1 = z1 > 0.f ? z1 : 0.01f * z1;
    float z2 = sc + sr.z; z2 = z2 > 0.f ? z2 : 0.01f * z2;
    float z3 = sc + sr.w; z3 = z3 > 0.f ? z3 : 0.01f * z3;
    denT8[idx] = pk_fp8x4(__expf(z0), __expf(z1), __expf(z2), __expf(z3));
}

// ---------------------------------------------------------------------------
// Kernel 4: num = A@den via MX-FP8 mfma_scale 32x32x64 (scale = 2^0).
// 128x128 tile, BK=64 bytes, 4 waves 2x2, each wave 2x2 of 32x32 frags.
// LDS chunk-swizzle: slot s of row r holds global 16B-chunk s ^ ((r>>1)&3),
// applied on the staging SOURCE address (gld_lds dest is lane-forced).
// Fused epilogue: att[i][j] = bf16(den/num), staged via LDS (stride 136 u16).
// ---------------------------------------------------------------------------
__global__ __launch_bounds__(256) void gemm_att_kernel(
    const uint8_t* __restrict__ Ab8, const uint8_t* __restrict__ Bt8,
    const float* __restrict__ s_row, const float* __restrict__ s_col,
    uint16_t* __restrict__ att) {
    __shared__ __align__(16) char smem[128 * 272];   // epilogue needs 34816 B; K-loop uses first 16 KB
    char* As = smem;
    char* Bs = smem + 8192;
    const int bm0 = blockIdx.y * 128, bn0 = blockIdx.x * 128;

    const int tid  = threadIdx.x;
    const int lane = tid & 63;
    const int wid  = tid >> 6;
    const int wy   = wid >> 1, wx = wid & 1;
    const int m    = lane & 31, h = lane >> 5;

    // staging: thread t fills LDS slot t*16 (row r = t>>2, slot s = t&3);
    // source chunk c = s ^ ((r>>1)&3)  (same swizzle for rows r and r+64)
    const int sr_ = tid >> 2;
    const int scb = (((tid & 3) ^ ((sr_ >> 1) & 3)) << 4);   // source byte offset in row

    f32x16 acc[2][2];
    #pragma unroll
    for (int mi = 0; mi < 2; ++mi)
        #pragma unroll
        for (int ni = 0; ni < 2; ++ni)
            #pragma unroll
            for (int r = 0; r < 16; ++r) acc[mi][ni][r] = 0.f;

    const int sw = (m >> 1) & 3;           // frag-read swizzle (uniform across frags)
    const int c0 = ((2 * h) ^ sw) << 4;
    const int c1 = ((2 * h + 1) ^ sw) << 4;

    for (int k0 = 0; k0 < NN; k0 += 64) {
        __syncthreads();
        gld_lds16(Ab8 + (size_t)(bm0 +      sr_) * NN + k0 + scb, As +        tid * 16);
        gld_lds16(Ab8 + (size_t)(bm0 + 64 + sr_) * NN + k0 + scb, As + 4096 + tid * 16);
        gld_lds16(Bt8 + (size_t)(bn0 +      sr_) * NN + k0 + scb, Bs +        tid * 16);
        gld_lds16(Bt8 + (size_t)(bn0 + 64 + sr_) * NN + k0 + scb, Bs + 4096 + tid * 16);
        __syncthreads();
        i32x8 af[2], bf[2];
        #pragma unroll
        for (int mi = 0; mi < 2; ++mi) {
            const char* p = As + (wy * 64 + mi * 32 + m) * 64;
            i32x4 lo = *(const i32x4*)(p + c0);
            i32x4 hi = *(const i32x4*)(p + c1);
            af[mi] = (i32x8){lo[0], lo[1], lo[2], lo[3], hi[0], hi[1], hi[2], hi[3]};
        }
        #pragma unroll
        for (int ni = 0; ni < 2; ++ni) {
            const char* p = Bs + (wx * 64 + ni * 32 + m) * 64;
            i32x4 lo = *(const i32x4*)(p + c0);
            i32x4 hi = *(const i32x4*)(p + c1);
            bf[ni] = (i32x8){lo[0], lo[1], lo[2], lo[3], hi[0], hi[1], hi[2], hi[3]};
        }
        #pragma unroll
        for (int mi = 0; mi < 2; ++mi)
            #pragma unroll
            for (int ni = 0; ni < 2; ++ni)
                acc[mi][ni] = __builtin_amdgcn_mfma_scale_f32_32x32x64_f8f6f4(
                    af[mi], bf[ni], acc[mi][ni], 0, 0,
                    0, 0x7F7F7F7F, 0, 0x7F7F7F7F);   // e8m0 127 = x1.0
    }

    __syncthreads();   // done reading As/Bs; reuse smem for epilogue staging
    uint16_t* smem16 = (uint16_t*)smem;

    // C/D layout (32x32): col = lane&31, row = (reg&3) + 8*(reg>>2) + 4*(lane>>5)
    #pragma unroll
    for (int ni = 0; ni < 2; ++ni) {
        const int jl = wx * 64 + ni * 32 + m;
        const float scj = s_col[bn0 + jl];
        #pragma unroll
        for (int mi = 0; mi < 2; ++mi) {
            #pragma unroll
            for (int reg = 0; reg < 16; ++reg) {
                const int row = (reg & 3) + 8 * (reg >> 2) + 4 * h;
                const int il = wy * 64 + mi * 32 + row;
                float z = s_row[bm0 + il] + scj;
                z = z > 0.f ? z : 0.01f * z;
                const float den = __expf(z);
                const float num = acc[mi][ni][reg];
                float v = den * __builtin_amdgcn_rcpf(num);
                v = (num != 0.f) ? v : 0.f;
                smem16[il * 136 + jl] = f2b(v);
            }
        }
    }
    __syncthreads();
    {
        const int row = tid >> 1, half = tid & 1;
        const u16x8* src = (const u16x8*)(smem16 + row * 136 + half * 64);
        u16x8* dst = (u16x8*)(att + (size_t)(bm0 + row) * NN + bn0 + half * 64);
        #pragma unroll
        for (int c = 0; c < 8; ++c) dst[c] = src[c];
    }
}

// ---------------------------------------------------------------------------
// bf16 GEMM core (m97 structure) for the skinny GEMMs
// ---------------------------------------------------------------------------
__device__ __forceinline__ void gemm_core(
    const uint16_t* __restrict__ Ab, const uint16_t* __restrict__ Bt,
    int bm0, int bn0, int kBeg, int kEnd, int K,
    uint16_t* As, uint16_t* Bs, f32x4 acc[4][4]) {
    const int tid  = threadIdx.x;
    const int lane = tid & 63;
    const int wid  = tid >> 6;
    const int wy   = wid >> 1, wx = wid & 1;
    const int quad = lane >> 4, l16 = lane & 15;
    const int byteoff = tid * 16;
    const int srow    = byteoff >> 6;
    const int scol    = (byteoff & 63) >> 1;

    for (int k0 = kBeg; k0 < kEnd; k0 += 32) {
        __syncthreads();
        gld_lds16(Ab + (size_t)(bm0 +      srow) * K + k0 + scol, (char*)As +        byteoff);
        gld_lds16(Ab + (size_t)(bm0 + 64 + srow) * K + k0 + scol, (char*)As + 4096 + byteoff);
        gld_lds16(Bt + (size_t)(bn0 +      srow) * K + k0 + scol, (char*)Bs +        byteoff);
        gld_lds16(Bt + (size_t)(bn0 + 64 + srow) * K + k0 + scol, (char*)Bs + 4096 + byteoff);
        __syncthreads();
        bf16x8 af[4], bf[4];
        #pragma unroll
        for (int mi = 0; mi < 4; ++mi)
            af[mi] = *(const bf16x8*)((const char*)As + ((wy * 64 + mi * 16 + l16) * 64 + quad * 16));
        #pragma unroll
        for (int ni = 0; ni < 4; ++ni)
            bf[ni] = *(const bf16x8*)((const char*)Bs + ((wx * 64 + ni * 16 + l16) * 64 + quad * 16));
        #pragma unroll
        for (int mi = 0; mi < 4; ++mi)
            #pragma unroll
            for (int ni = 0; ni < 4; ++ni)
                acc[mi][ni] = __builtin_amdgcn_mfma_f32_16x16x32_bf16(af[mi], bf[ni], acc[mi][ni], 0, 0, 0);
    }
}

// ---------------------------------------------------------------------------
// Kernel 5: skinny GEMM split-K, P stored column-major per split: P[split][j][i]
// ---------------------------------------------------------------------------
__global__ __launch_bounds__(256) void gemm_splitk_kernel(
    const uint16_t* __restrict__ Ab, const uint16_t* __restrict__ Bt,
    float* __restrict__ P) {
    __shared__ __align__(16) uint16_t As[128 * 32];
    __shared__ __align__(16) uint16_t Bs[128 * 32];
    const int bm0 = blockIdx.y * 128;
    const int split = blockIdx.z;
    const int chunk = NN / NSPLIT;
    f32x4 acc[4][4];
    #pragma unroll
    for (int mi = 0; mi < 4; ++mi)
        #pragma unroll
        for (int ni = 0; ni < 4; ++ni)
            acc[mi][ni] = (f32x4){0.f, 0.f, 0.f, 0.f};

    gemm_core(Ab, Bt, bm0, 0, split * chunk, (split + 1) * chunk, NN, As, Bs, acc);

    const int lane = threadIdx.x & 63, wid = threadIdx.x >> 6;
    const int wy = wid >> 1, wx = wid & 1;
    const int quad = lane >> 4, l16 = lane & 15;
    float* Pp = P + (size_t)split * (NN * NF);
    #pragma unroll
    for (int mi = 0; mi < 4; ++mi) {
        const int i0 = bm0 + wy * 64 + mi * 16 + quad * 4;
        #pragma unroll
        for (int ni = 0; ni < 4; ++ni) {
            const int j = wx * 64 + ni * 16 + l16;
            *(f32x4*)(Pp + (size_t)j * NN + i0) = acc[mi][ni];
        }
    }
}

// ---------------------------------------------------------------------------
// Reduce kernels (P is [split][j][i] col-major)
// ---------------------------------------------------------------------------
__global__ void reduce_t_kernel(const float* __restrict__ P, uint16_t* __restrict__ M1T) {
    int idx = blockIdx.x * 256 + threadIdx.x;
    float s = 0.f;
    #pragma unroll
    for (int sp = 0; sp < NSPLIT; ++sp) s += P[(size_t)sp * (NN * NF) + idx];
    M1T[idx] = f2b(s);
}

__global__ void reduce_out_kernel(const float* __restrict__ P, float* __restrict__ out) {
    int idx = blockIdx.x * 256 + threadIdx.x;
    float s = 0.f;
    #pragma unroll
    for (int sp = 0; sp < NSPLIT; ++sp) s += P[(size_t)sp * (NN * NF) + idx];
    int j = idx >> 12, i = idx & 4095;
    out[(size_t)i * NF + j] = s;
}

// ---------------------------------------------------------------------------
extern "C" void kernel_launch(void* const* d_in, const int* in_sizes, int n_in,
                              void* d_out, int out_size, void* d_ws, size_t ws_size,
                              hipStream_t stream) {
    (void)in_sizes; (void)n_in; (void)out_size; (void)ws_size;
    const float* X = (const float*)d_in[0];
    const float* A = (const float*)d_in[1];
    const float* W = (const float*)d_in[2];
    const float* a = (const float*)d_in[3];
    float* H = (float*)d_out;

    char* ws = (char*)d_ws;
    uint16_t* Ab    = (uint16_t*)(ws);                          // 32 MB (bf16 A, skinny GEMM)
    uint32_t* denT8 = (uint32_t*)(ws + ((size_t)32 << 20));     // 16 MB fp8
    uint8_t*  Ab8   = (uint8_t*) (ws + ((size_t)48 << 20));     // 16 MB fp8
    float*    P     = (float*)   (ws + ((size_t)32 << 20));     // 32 MB, overlays denT8+Ab8 (dead after gemm_att)
    uint16_t* att   = (uint16_t*)(ws + ((size_t)64 << 20));     // 32 MB
    uint16_t* XWT   = (uint16_t*)(ws + ((size_t)96 << 20));     // 1 MB
    uint16_t* M1T   = (uint16_t*)(ws + ((size_t)97 << 20));     // 1 MB
    float*    s_col = (float*)   (ws + ((size_t)98 << 20));     // 16 KB
    float*    s_row = (float*)   (ws + ((size_t)98 << 20) + 16384);

    // 1. XW + scores (+ XWT bf16)
    xw_kernel<<<NN, NF, 0, stream>>>(X, W, a, XWT, s_col, s_row);
    // 2. A -> bf16 + fp8
    conv_kernel<<<(NN * NN / 4) / 256, 256, 0, stream>>>(A, Ab, (uint32_t*)Ab8);
    // 3. denT fp8
    denT_kernel<<<(NN * 1024) / 256, 256, 0, stream>>>(s_row, s_col, denT8);
    // 4. num = A@den (MX-FP8) with fused att epilogue
    gemm_att_kernel<<<dim3(32, 32), 256, 0, stream>>>(Ab8, (const uint8_t*)denT8, s_row, s_col, att);
    // 5. M1 = att @ XW (split-K partials; P overlays dead fp8 buffers)
    gemm_splitk_kernel<<<dim3(1, 32, NSPLIT), 256, 0, stream>>>(att, XWT, P);
    // 6. reduce -> M1T bf16 (col-major == B^T operand)
    reduce_t_kernel<<<(NN * NF) / 256, 256, 0, stream>>>(P, M1T);
    // 7. H = A @ M1 (split-K partials)
    gemm_splitk_kernel<<<dim3(1, 32, NSPLIT), 256, 0, stream>>>(Ab, M1T, P);
    // 8. reduce -> output
    reduce_out_kernel<<<(NN * NF) / 256, 256, 0, stream>>>(P, H);
}